// Round 1
// 145.029 us; speedup vs baseline: 1.1046x; 1.1046x over previous
//
#include <hip/hip_runtime.h>
#include <hip/hip_bf16.h>

// Problem constants
#define VD 160           // vol D=H=W
#define OD 128           // output crop size
#define CROP0 16         // (160-128)/2
#define FSZ 11           // cropped field size
#define RAWSZ 15         // raw field size
#define NBATCH 4
#define ODQ 4            // outputs per thread along od

// e-table layout: [c][oh_l][od_l][ESTR]; ESTR=17 -> oh stride 136 floats,
// banks for the 4 hl-groups = {0,8,16,24}: conflict-free.
#define ESTR 17
#define EOH  (8*ESTR)      // 136
#define ECH  (8*8*ESTR)    // 1088

// ---------------------------------------------------------------------------
// Kernel 1: field prep (blocks 0..2) + Rodrigues/theta (block 3).
// 1024 threads; per-chunk (z,y,x) hoisted out of the 12 smoothing passes.
// ---------------------------------------------------------------------------
__global__ __launch_bounds__(1024) void prep_kernel(
        const float* __restrict__ rot, const float* __restrict__ scale,
        const float* __restrict__ shift,
        const float* __restrict__ dz, const float* __restrict__ dy,
        const float* __restrict__ dx,
        float* __restrict__ theta, float* __restrict__ fields) {
    const int tid = threadIdx.x;
    const int chan = blockIdx.x;

    if (chan == 3) {
        int n = tid;
        if (n >= NBATCH) return;
        float rx = rot[n*3+0], ry = rot[n*3+1], rz = rot[n*3+2];
        float t2 = rx*rx + ry*ry + rz*rz;
        const float eps = 1e-6f;
        float th = sqrtf(fmaxf(t2, eps));
        float inv = 1.0f / (th + eps);
        float wx = rx*inv, wy = ry*inv, wz = rz*inv;
        float c = cosf(th), s = sinf(th), k = 1.0f - c;
        float R[9];
        if (t2 > eps) {
            R[0] = c + wx*wx*k;      R[1] = wx*wy*k - wz*s;  R[2] = wy*s + wx*wz*k;
            R[3] = wz*s + wx*wy*k;   R[4] = c + wy*wy*k;     R[5] = -wx*s + wy*wz*k;
            R[6] = -wy*s + wx*wz*k;  R[7] = wx*s + wy*wz*k;  R[8] = c + wz*wz*k;
        } else {
            R[0] = 1.0f; R[1] = -rz;  R[2] = ry;
            R[3] = rz;   R[4] = 1.0f; R[5] = -rx;
            R[6] = -ry;  R[7] = rx;   R[8] = 1.0f;
        }
        for (int i = 0; i < 3; ++i) {
            for (int j = 0; j < 3; ++j)
                theta[n*12 + i*4 + j] = R[i*3 + j] * scale[n*3 + j];
            theta[n*12 + i*4 + 3] = shift[n*3 + i];
        }
        return;
    }

    __shared__ float bufA[RAWSZ*RAWSZ*RAWSZ];
    __shared__ float bufB[RAWSZ*RAWSZ*RAWSZ];
    const float* raw = (chan == 0) ? dz : (chan == 1) ? dy : dx;
    const int NTOT = RAWSZ*RAWSZ*RAWSZ;   // 3375

    for (int i = tid; i < NTOT; i += 1024)
        bufA[i] = (raw[i] - 0.5f) * 4.0f;

    // precompute (z,y,x) per chunk once (compile-time-indexed arrays -> regs)
    int cz[4], cy[4], cxx[4];
    bool val[4];
    #pragma unroll
    for (int j = 0; j < 4; ++j) {
        const int i = tid + j*1024;
        val[j] = (i < NTOT);
        const int ii = val[j] ? i : 0;
        cz[j]  = ii / (RAWSZ*RAWSZ);
        const int r = ii % (RAWSZ*RAWSZ);
        cy[j]  = r / RAWSZ;
        cxx[j] = r % RAWSZ;
    }
    __syncthreads();

    float* src = bufA;
    float* dst = bufB;
    for (int it = 0; it < 4; ++it) {
        #pragma unroll
        for (int ax = 0; ax < 3; ++ax) {
            const int stride = (ax == 0) ? RAWSZ*RAWSZ : (ax == 1) ? RAWSZ : 1;
            #pragma unroll
            for (int j = 0; j < 4; ++j) {
                if (val[j]) {
                    const int i = tid + j*1024;
                    const int c = (ax == 0) ? cz[j] : (ax == 1) ? cy[j] : cxx[j];
                    const int ib = i - c*stride;   // base with c removed
                    float s = 0.0f;
                    #pragma unroll
                    for (int t = -2; t <= 2; ++t) {
                        const int cc = min(max(c + t, 0), RAWSZ - 1);
                        s += src[ib + cc*stride];
                    }
                    dst[i] = s * 0.2f;
                }
            }
            __syncthreads();
            float* tmp = src; src = dst; dst = tmp;
        }
    }
    for (int i = tid; i < FSZ*FSZ*FSZ; i += 1024) {
        const int z = i / (FSZ*FSZ);
        const int r = i % (FSZ*FSZ);
        const int y = r / FSZ;
        const int x = r % FSZ;
        fields[chan*FSZ*FSZ*FSZ + i] =
            src[(z+2)*RAWSZ*RAWSZ + (y+2)*RAWSZ + (x+2)];
    }
}

// ---------------------------------------------------------------------------
// resize helper: src = (m+0.5)*(11/160) - 0.5, clipped to [0,10]
// ---------------------------------------------------------------------------
__device__ __forceinline__ void resize_coord(int m, int& i0, int& i1, float& w) {
    float s = fmaf((float)m + 0.5f, (float)FSZ / (float)VD, -0.5f);
    s = fminf(fmaxf(s, 0.0f), (float)(FSZ - 1));
    float f = floorf(s);
    i0 = (int)f;
    i1 = min(i0 + 1, FSZ - 1);
    w = s - f;
}

// ---------------------------------------------------------------------------
// Kernel 2: main sampler.
// Wave lane map = 16(ow) x 4(oh); block = 512 thr = 8 waves (2wx x 2wh x 2wd);
// block tile = 32(w) x 8(h) x 8(d); each thread does ODQ=4 od's.
// e[c][oh_l][od_l][17]: (z,y)-bilinear of disp at 11 x-knots, x80.
// NEW: wave-uniform interior fast path (no clamps / no predicated weights),
//      hoisted e-fill (3 resize_coord + 8 weights + 8 offsets per thread).
// grid = (OD/32, OD/8, (OD/8)*NBATCH).
// ---------------------------------------------------------------------------
__global__ __launch_bounds__(512) void sample_kernel(
        const float* __restrict__ vol, const float* __restrict__ theta,
        const float* __restrict__ fields, float* __restrict__ out) {
    __shared__ float e[3*ECH];   // 3*1088 floats = 13056 B

    const int tid  = threadIdx.x;
    const int lane = tid & 63;
    const int wl   = lane & 15;        // x within wave patch
    const int hl   = lane >> 4;        // y within wave patch (0..3)
    const int wv   = tid >> 6;         // wave id 0..7
    const int wx   = wv & 1;
    const int wh   = (wv >> 1) & 1;
    const int wd   = wv >> 2;          // 0..1

    const int ow_l = (wx << 4) | wl;       // 0..31
    const int oh_l = (wh << 2) | hl;       // 0..7
    const int ow   = (blockIdx.x << 5) | ow_l;
    const int oh   = (blockIdx.y << 3) | oh_l;
    const int odb  = (blockIdx.z & 15) << 3;   // od block base (0..120)
    const int n    = blockIdx.z >> 4;

    // ---- e fill: slot map is affine in i: xi,eod const; eoh in {eoh0,eoh0+4};
    //      c = i>>1. Hoist resize_coord (3x) + zy-weights + field offsets. ----
    {
        const int xi   = tid & 15;
        const int row0 = tid >> 4;          // 0..31
        if (xi < FSZ) {
            const int eod  = row0 & 7;
            const int eoh0 = row0 >> 3;     // 0..3
            int zi0, zi1, yA0, yA1, yB0, yB1;
            float zw, ywA, ywB;
            resize_coord(odb + eod + CROP0, zi0, zi1, zw);
            const int hbase = (blockIdx.y << 3) + CROP0;
            resize_coord(hbase + eoh0,     yA0, yA1, ywA);
            resize_coord(hbase + eoh0 + 4, yB0, yB1, ywB);
            const float wz0 = 1.0f - zw;
            const float wA00 = wz0*(1.0f-ywA), wA01 = wz0*ywA;
            const float wA10 = zw*(1.0f-ywA),  wA11 = zw*ywA;
            const float wB00 = wz0*(1.0f-ywB), wB01 = wz0*ywB;
            const float wB10 = zw*(1.0f-ywB),  wB11 = zw*ywB;
            const int oA00 = zi0*121 + yA0*11 + xi, oA01 = zi0*121 + yA1*11 + xi;
            const int oA10 = zi1*121 + yA0*11 + xi, oA11 = zi1*121 + yA1*11 + xi;
            const int oB00 = zi0*121 + yB0*11 + xi, oB01 = zi0*121 + yB1*11 + xi;
            const int oB10 = zi1*121 + yB0*11 + xi, oB11 = zi1*121 + yB1*11 + xi;
            float* ew = &e[row0*ESTR + xi];     // row row0+32*i -> +i*32*ESTR
            #pragma unroll
            for (int i = 0; i < 6; ++i) {
                const float* f = fields + (i >> 1) * (FSZ*FSZ*FSZ);
                float v;
                if (i & 1)
                    v = f[oB00]*wB00 + f[oB01]*wB01 + f[oB10]*wB10 + f[oB11]*wB11;
                else
                    v = f[oA00]*wA00 + f[oA01]*wA01 + f[oA10]*wA10 + f[oA11]*wA11;
                ew[i * (32*ESTR)] = v * 80.0f;  // voxel units
            }
        }
    }
    __syncthreads();

    const int w_ = ow + CROP0;
    const int h_ = oh + CROP0;

    const float x = fmaf(2.0f * (float)w_ + 1.0f, 1.0f / (float)VD, -1.0f);
    const float y = fmaf(2.0f * (float)h_ + 1.0f, 1.0f / (float)VD, -1.0f);

    // x-knot: s in [0.63, 9.38] for valid w_ -> xi0<=9, xi1=xi0+1 always
    float s = fmaf((float)w_ + 0.5f, (float)FSZ / (float)VD, -0.5f);
    s = fminf(fmaxf(s, 0.0f), (float)(FSZ - 1));
    const float sf = floorf(s);
    const int   xi0 = (int)sf;
    const float xw  = s - sf;

    const float* th = theta + n*12;
    const float cx = fmaf(th[0]*x + th[1]*y + th[3], 80.0f, 79.5f);
    const float cy = fmaf(th[4]*x + th[5]*y + th[7], 80.0f, 79.5f);
    const float cz = fmaf(th[8]*x + th[9]*y + th[11], 80.0f, 79.5f);
    const float tz0 = th[2] * 80.0f, tz1 = th[6] * 80.0f, tz2 = th[10] * 80.0f;

    const float* v = vol + (size_t)n * (VD*VD*VD);

    // single vaddr for all e reads; (c,k) parts are immediate offsets
    const float* ebase = &e[oh_l*EOH + (wd << 2)*ESTR + xi0];

    const int dbase = odb + (wd << 2) + CROP0;
    const float zb = fmaf(2.0f * (float)dbase + 1.0f, 1.0f / (float)VD, -1.0f);
    float* op = out + ((((size_t)n*OD + (odb + (wd << 2)))*OD + oh)*OD + ow);

    #pragma unroll
    for (int k = 0; k < ODQ; ++k) {
        const float z = zb + (float)k * (2.0f / (float)VD);

        const float ex0 = ebase[        k*ESTR    ], ex1 = ebase[        k*ESTR + 1];
        const float ey0 = ebase[ECH   + k*ESTR    ], ey1 = ebase[ECH   + k*ESTR + 1];
        const float ez0 = ebase[2*ECH + k*ESTR    ], ez1 = ebase[2*ECH + k*ESTR + 1];
        const float d80x = fmaf(ex1 - ex0, xw, ex0);
        const float d80y = fmaf(ey1 - ey0, xw, ey0);
        const float d80z = fmaf(ez1 - ez0, xw, ez0);

        const float xs = fmaf(tz0, z, cx) + d80x;
        const float ys = fmaf(tz1, z, cy) + d80y;
        const float zs = fmaf(tz2, z, cz) + d80z;

        const float x0f = floorf(xs), y0f = floorf(ys), z0f = floorf(zs);
        const float fx = xs - x0f, fy = ys - y0f, fz = zs - z0f;
        const int ix0 = (int)x0f, iy0 = (int)y0f, iz0 = (int)z0f;

        float r;
        const int inb = ((unsigned)ix0 < (unsigned)(VD-1)) &
                        ((unsigned)iy0 < (unsigned)(VD-1)) &
                        ((unsigned)iz0 < (unsigned)(VD-1));
        if (__all(inb)) {
            // ---- interior fast path: pure lerp chain, trivial addressing ----
            const int b00 = (iz0*VD + iy0)*VD + ix0;
            float2 p00, p01, p10, p11;
            __builtin_memcpy(&p00, v + b00,             sizeof(float2));
            __builtin_memcpy(&p01, v + b00 + VD,        sizeof(float2));
            __builtin_memcpy(&p10, v + b00 + VD*VD,     sizeof(float2));
            __builtin_memcpy(&p11, v + b00 + VD*VD+VD,  sizeof(float2));
            const float r00 = fmaf(fx, p00.y - p00.x, p00.x);
            const float r01 = fmaf(fx, p01.y - p01.x, p01.x);
            const float r10 = fmaf(fx, p10.y - p10.x, p10.x);
            const float r11 = fmaf(fx, p11.y - p11.x, p11.x);
            const float r0 = fmaf(fy, r01 - r00, r00);
            const float r1 = fmaf(fy, r11 - r10, r10);
            r = fmaf(fz, r1 - r0, r0);
        } else {
            // ---- border path: full predicated weights + clamps ----
            const int ix1 = ix0 + 1,  iy1 = iy0 + 1,  iz1 = iz0 + 1;

            const float WX0 = ((unsigned)ix0 < (unsigned)VD) ? (1.0f - fx) : 0.0f;
            const float WX1 = ((unsigned)ix1 < (unsigned)VD) ? fx          : 0.0f;
            const float WY0 = ((unsigned)iy0 < (unsigned)VD) ? (1.0f - fy) : 0.0f;
            const float WY1 = ((unsigned)iy1 < (unsigned)VD) ? fy          : 0.0f;
            const float WZ0 = ((unsigned)iz0 < (unsigned)VD) ? (1.0f - fz) : 0.0f;
            const float WZ1 = ((unsigned)iz1 < (unsigned)VD) ? fz          : 0.0f;

            const int xc0 = min(max(ix0, 0), VD-1), xc1 = min(max(ix1, 0), VD-1);
            const int yc0 = min(max(iy0, 0), VD-1), yc1 = min(max(iy1, 0), VD-1);
            const int zc0 = min(max(iz0, 0), VD-1), zc1 = min(max(iz1, 0), VD-1);

            // one dwordx2 covers both x-taps; fold x-selection into wA/wB
            const int base = min(xc0, VD-2);
            const bool hi0 = (xc0 != base);
            const bool hi1 = (xc1 != base);
            const float wA = (hi0 ? 0.0f : WX0) + (hi1 ? 0.0f : WX1);
            const float wB = (hi0 ? WX0 : 0.0f) + (hi1 ? WX1 : 0.0f);

            const int sA = zc0*(VD*VD), sB = zc1*(VD*VD);
            const int tA = yc0*VD + base, tB = yc1*VD + base;

            float2 p00, p01, p10, p11;
            __builtin_memcpy(&p00, v + sA + tA, sizeof(float2));
            __builtin_memcpy(&p01, v + sA + tB, sizeof(float2));
            __builtin_memcpy(&p10, v + sB + tA, sizeof(float2));
            __builtin_memcpy(&p11, v + sB + tB, sizeof(float2));

            const float r00 = p00.x*wA + p00.y*wB;
            const float r01 = p01.x*wA + p01.y*wB;
            const float r10 = p10.x*wA + p10.y*wB;
            const float r11 = p11.x*wA + p11.y*wB;
            r = (r00*WY0 + r01*WY1)*WZ0 + (r10*WY0 + r11*WY1)*WZ1;
        }

        op[(size_t)k*OD*OD] = r;
    }
}

// ---------------------------------------------------------------------------
extern "C" void kernel_launch(void* const* d_in, const int* in_sizes, int n_in,
                              void* d_out, int out_size, void* d_ws, size_t ws_size,
                              hipStream_t stream) {
    const float* vol   = (const float*)d_in[0];
    const float* rot   = (const float*)d_in[1];
    const float* scale = (const float*)d_in[2];
    const float* shift = (const float*)d_in[3];
    const float* dz    = (const float*)d_in[4];
    const float* dy    = (const float*)d_in[5];
    const float* dx    = (const float*)d_in[6];
    float* out = (float*)d_out;

    float* ws     = (float*)d_ws;
    float* theta  = ws;         // 4*12 = 48 floats
    float* fields = ws + 48;    // 3*1331 floats

    prep_kernel<<<4, 1024, 0, stream>>>(rot, scale, shift, dz, dy, dx,
                                        theta, fields);
    dim3 grid(OD/32, OD/8, (OD/8)*NBATCH);
    sample_kernel<<<grid, 512, 0, stream>>>(vol, theta, fields, out);
}

// Round 2
// 143.555 us; speedup vs baseline: 1.1160x; 1.0103x over previous
//
#include <hip/hip_runtime.h>

// Problem constants
#define VD 160           // vol D=H=W
#define OD 128           // output crop size
#define CROP0 16         // (160-128)/2
#define FSZ 11           // cropped field size
#define RAWSZ 15         // raw field size
#define NBATCH 4
#define ODQ 4            // outputs per thread along od

// e-table layout: [c][oh_l][od_l][ESTR]; ESTR=17 -> oh stride 136 floats,
// banks for the 4 hl-groups = {0,8,16,24}: conflict-free.
#define ESTR 17
#define EOH  (8*ESTR)      // 136
#define ECH  (8*8*ESTR)    // 1088

// ---------------------------------------------------------------------------
// Compile-time (box-5 edge-clamp)^4 as a 15x15 matrix: 4 smoothing iterations
// per axis collapse into one 15-tap linear pass (operators on distinct axes
// commute; per-axis operator is B^4).
// ---------------------------------------------------------------------------
struct M15 { float v[15][15]; };
constexpr M15 mkB() {
    M15 b{};
    for (int i = 0; i < 15; ++i)
        for (int j = 0; j < 15; ++j) b.v[i][j] = 0.0f;
    for (int i = 0; i < 15; ++i)
        for (int t = -2; t <= 2; ++t) {
            int j = i + t; j = j < 0 ? 0 : (j > 14 ? 14 : j);
            b.v[i][j] += 0.2f;
        }
    return b;
}
constexpr M15 mmul(const M15& a, const M15& b) {
    M15 c{};
    for (int i = 0; i < 15; ++i)
        for (int j = 0; j < 15; ++j) {
            float s = 0.0f;
            for (int k = 0; k < 15; ++k) s += a.v[i][k] * b.v[k][j];
            c.v[i][j] = s;
        }
    return c;
}
constexpr M15 B2 = mmul(mkB(), mkB());
constexpr M15 B4 = mmul(B2, B2);

// ---------------------------------------------------------------------------
// Kernel 1: field prep (blocks 0..2) + Rodrigues/theta (block 3).
// 3 matrix passes (x,y,z) + crop folded in: 4 barriers instead of 13.
// ---------------------------------------------------------------------------
__global__ __launch_bounds__(1024) void prep_kernel(
        const float* __restrict__ rot, const float* __restrict__ scale,
        const float* __restrict__ shift,
        const float* __restrict__ dz, const float* __restrict__ dy,
        const float* __restrict__ dx,
        float* __restrict__ theta, float* __restrict__ fields) {
    const int tid = threadIdx.x;
    const int chan = blockIdx.x;

    if (chan == 3) {
        int n = tid;
        if (n >= NBATCH) return;
        float rx = rot[n*3+0], ry = rot[n*3+1], rz = rot[n*3+2];
        float t2 = rx*rx + ry*ry + rz*rz;
        const float eps = 1e-6f;
        float th = sqrtf(fmaxf(t2, eps));
        float inv = 1.0f / (th + eps);
        float wx = rx*inv, wy = ry*inv, wz = rz*inv;
        float c = cosf(th), s = sinf(th), k = 1.0f - c;
        float R[9];
        if (t2 > eps) {
            R[0] = c + wx*wx*k;      R[1] = wx*wy*k - wz*s;  R[2] = wy*s + wx*wz*k;
            R[3] = wz*s + wx*wy*k;   R[4] = c + wy*wy*k;     R[5] = -wx*s + wy*wz*k;
            R[6] = -wy*s + wx*wz*k;  R[7] = wx*s + wy*wz*k;  R[8] = c + wz*wz*k;
        } else {
            R[0] = 1.0f; R[1] = -rz;  R[2] = ry;
            R[3] = rz;   R[4] = 1.0f; R[5] = -rx;
            R[6] = -ry;  R[7] = rx;   R[8] = 1.0f;
        }
        for (int i = 0; i < 3; ++i) {
            for (int j = 0; j < 3; ++j)
                theta[n*12 + i*4 + j] = R[i*3 + j] * scale[n*3 + j];
            theta[n*12 + i*4 + 3] = shift[n*3 + i];
        }
        return;
    }

    __shared__ float bufA[RAWSZ*RAWSZ*RAWSZ];   // raw scaled  [z][y][x]
    __shared__ float bufB[RAWSZ*RAWSZ*FSZ];     // x-pass out  [z][y][xo]
    __shared__ float bufC[RAWSZ*FSZ*FSZ];       // y-pass out  [z][yo][xo]
    const float* raw = (chan == 0) ? dz : (chan == 1) ? dy : dx;
    const int NTOT = RAWSZ*RAWSZ*RAWSZ;   // 3375

    for (int i = tid; i < NTOT; i += 1024)
        bufA[i] = (raw[i] - 0.5f) * 4.0f;
    __syncthreads();

    // x pass: 15*15*11 = 2475 outputs; out xo = crop row xo+2 of B4
    for (int i = tid; i < RAWSZ*RAWSZ*FSZ; i += 1024) {
        const int zy = i / FSZ;
        const int xo = i % FSZ;
        const float* row = &bufA[zy * RAWSZ];
        const float* w = B4.v[xo + 2];
        float s = 0.0f;
        #pragma unroll
        for (int j = 0; j < RAWSZ; ++j) s += row[j] * w[j];
        bufB[i] = s;
    }
    __syncthreads();

    // y pass: 15*11*11 = 1815 outputs
    for (int i = tid; i < RAWSZ*FSZ*FSZ; i += 1024) {
        const int z  = i / (FSZ*FSZ);
        const int r  = i % (FSZ*FSZ);
        const int yo = r / FSZ;
        const int xo = r % FSZ;
        const float* base = &bufB[z * (RAWSZ*FSZ) + xo];
        const float* w = B4.v[yo + 2];
        float s = 0.0f;
        #pragma unroll
        for (int j = 0; j < RAWSZ; ++j) s += base[j * FSZ] * w[j];
        bufC[i] = s;
    }
    __syncthreads();

    // z pass: 11*11*11 = 1331 outputs -> fields
    for (int i = tid; i < FSZ*FSZ*FSZ; i += 1024) {
        const int zo = i / (FSZ*FSZ);
        const int r  = i % (FSZ*FSZ);
        const float* base = &bufC[r];
        const float* w = B4.v[zo + 2];
        float s = 0.0f;
        #pragma unroll
        for (int j = 0; j < RAWSZ; ++j) s += base[j * (FSZ*FSZ)] * w[j];
        fields[chan*FSZ*FSZ*FSZ + i] = s;
    }
}

// ---------------------------------------------------------------------------
// resize helper: src = (m+0.5)*(11/160) - 0.5, clipped to [0,10]
// ---------------------------------------------------------------------------
__device__ __forceinline__ void resize_coord(int m, int& i0, int& i1, float& w) {
    float s = fmaf((float)m + 0.5f, (float)FSZ / (float)VD, -0.5f);
    s = fminf(fmaxf(s, 0.0f), (float)(FSZ - 1));
    float f = floorf(s);
    i0 = (int)f;
    i1 = min(i0 + 1, FSZ - 1);
    w = s - f;
}

// ---------------------------------------------------------------------------
// Kernel 2: main sampler.
// Wave lane map = 16(ow) x 4(oh); block = 512 thr = 8 waves (2wx x 2wh x 2wd);
// block tile = 32(w) x 8(h) x 8(d); each thread does ODQ=4 od's.
// NEW this round: all 4 k-iterations batched — 12 e-pair LDS reads, 4 coord
// triples, one wave-uniform interiority test, then ALL 16 gather loads issued
// before any consumption (memory-level parallelism; kernel was latency-bound
// at VGPR=32 with serialized per-k gathers: VALUBusy 41%, HBM 22%, occ 60%).
// __launch_bounds__(512,4): VGPR cap 128, min 2 blocks/CU.
// grid = (OD/32, OD/8, (OD/8)*NBATCH).
// ---------------------------------------------------------------------------
__global__ __launch_bounds__(512, 4) void sample_kernel(
        const float* __restrict__ vol, const float* __restrict__ theta,
        const float* __restrict__ fields, float* __restrict__ out) {
    __shared__ float e[3*ECH];   // 3*1088 floats = 13056 B

    const int tid  = threadIdx.x;
    const int lane = tid & 63;
    const int wl   = lane & 15;        // x within wave patch
    const int hl   = lane >> 4;        // y within wave patch (0..3)
    const int wv   = tid >> 6;         // wave id 0..7
    const int wx   = wv & 1;
    const int wh   = (wv >> 1) & 1;
    const int wd   = wv >> 2;          // 0..1

    const int ow_l = (wx << 4) | wl;       // 0..31
    const int oh_l = (wh << 2) | hl;       // 0..7
    const int ow   = (blockIdx.x << 5) | ow_l;
    const int oh   = (blockIdx.y << 3) | oh_l;
    const int odb  = (blockIdx.z & 15) << 3;   // od block base (0..120)
    const int n    = blockIdx.z >> 4;

    // ---- e fill: hoisted resize_coord (3x) + zy-weights + field offsets ----
    {
        const int xi   = tid & 15;
        const int row0 = tid >> 4;          // 0..31
        if (xi < FSZ) {
            const int eod  = row0 & 7;
            const int eoh0 = row0 >> 3;     // 0..3
            int zi0, zi1, yA0, yA1, yB0, yB1;
            float zw, ywA, ywB;
            resize_coord(odb + eod + CROP0, zi0, zi1, zw);
            const int hbase = (blockIdx.y << 3) + CROP0;
            resize_coord(hbase + eoh0,     yA0, yA1, ywA);
            resize_coord(hbase + eoh0 + 4, yB0, yB1, ywB);
            const float wz0 = 1.0f - zw;
            const float wA00 = wz0*(1.0f-ywA), wA01 = wz0*ywA;
            const float wA10 = zw*(1.0f-ywA),  wA11 = zw*ywA;
            const float wB00 = wz0*(1.0f-ywB), wB01 = wz0*ywB;
            const float wB10 = zw*(1.0f-ywB),  wB11 = zw*ywB;
            const int oA00 = zi0*121 + yA0*11 + xi, oA01 = zi0*121 + yA1*11 + xi;
            const int oA10 = zi1*121 + yA0*11 + xi, oA11 = zi1*121 + yA1*11 + xi;
            const int oB00 = zi0*121 + yB0*11 + xi, oB01 = zi0*121 + yB1*11 + xi;
            const int oB10 = zi1*121 + yB0*11 + xi, oB11 = zi1*121 + yB1*11 + xi;
            float* ew = &e[row0*ESTR + xi];     // row row0+32*i -> +i*32*ESTR
            #pragma unroll
            for (int i = 0; i < 6; ++i) {
                const float* f = fields + (i >> 1) * (FSZ*FSZ*FSZ);
                float v;
                if (i & 1)
                    v = f[oB00]*wB00 + f[oB01]*wB01 + f[oB10]*wB10 + f[oB11]*wB11;
                else
                    v = f[oA00]*wA00 + f[oA01]*wA01 + f[oA10]*wA10 + f[oA11]*wA11;
                ew[i * (32*ESTR)] = v * 80.0f;  // voxel units
            }
        }
    }

    // ---- per-thread setup (before barrier: overlaps e-fill latency) ----
    const int w_ = ow + CROP0;
    const int h_ = oh + CROP0;

    const float x = fmaf(2.0f * (float)w_ + 1.0f, 1.0f / (float)VD, -1.0f);
    const float y = fmaf(2.0f * (float)h_ + 1.0f, 1.0f / (float)VD, -1.0f);

    // x-knot: s in [0.63, 9.38] for valid w_ -> xi0<=9, xi1=xi0+1 always
    float s = fmaf((float)w_ + 0.5f, (float)FSZ / (float)VD, -0.5f);
    s = fminf(fmaxf(s, 0.0f), (float)(FSZ - 1));
    const float sf = floorf(s);
    const int   xi0 = (int)sf;
    const float xw  = s - sf;

    const float* th = theta + n*12;
    const float cx = fmaf(th[0]*x + th[1]*y + th[3], 80.0f, 79.5f);
    const float cy = fmaf(th[4]*x + th[5]*y + th[7], 80.0f, 79.5f);
    const float cz = fmaf(th[8]*x + th[9]*y + th[11], 80.0f, 79.5f);
    const float tz0 = th[2] * 80.0f, tz1 = th[6] * 80.0f, tz2 = th[10] * 80.0f;

    const float* v = vol + (size_t)n * (VD*VD*VD);

    const float* ebase = &e[oh_l*EOH + (wd << 2)*ESTR + xi0];

    const int dbase = odb + (wd << 2) + CROP0;
    const float zb = fmaf(2.0f * (float)dbase + 1.0f, 1.0f / (float)VD, -1.0f);
    float* op = out + ((((size_t)n*OD + (odb + (wd << 2)))*OD + oh)*OD + ow);

    __syncthreads();

    // ---- batched e reads: 12 pairs, all independent ----
    float ex0[ODQ], ex1[ODQ], ey0[ODQ], ey1[ODQ], ez0[ODQ], ez1[ODQ];
    #pragma unroll
    for (int k = 0; k < ODQ; ++k) {
        ex0[k] = ebase[        k*ESTR    ];  ex1[k] = ebase[        k*ESTR + 1];
        ey0[k] = ebase[ECH   + k*ESTR    ];  ey1[k] = ebase[ECH   + k*ESTR + 1];
        ez0[k] = ebase[2*ECH + k*ESTR    ];  ez1[k] = ebase[2*ECH + k*ESTR + 1];
    }

    // ---- batched coords ----
    float fx[ODQ], fy[ODQ], fz[ODQ];
    int ix[ODQ], iy[ODQ], iz[ODQ];
    int inb = 1;
    #pragma unroll
    for (int k = 0; k < ODQ; ++k) {
        const float z = zb + (float)k * (2.0f / (float)VD);
        const float d80x = fmaf(ex1[k] - ex0[k], xw, ex0[k]);
        const float d80y = fmaf(ey1[k] - ey0[k], xw, ey0[k]);
        const float d80z = fmaf(ez1[k] - ez0[k], xw, ez0[k]);
        const float xs = fmaf(tz0, z, cx) + d80x;
        const float ys = fmaf(tz1, z, cy) + d80y;
        const float zs = fmaf(tz2, z, cz) + d80z;
        const float x0f = floorf(xs), y0f = floorf(ys), z0f = floorf(zs);
        fx[k] = xs - x0f; fy[k] = ys - y0f; fz[k] = zs - z0f;
        ix[k] = (int)x0f; iy[k] = (int)y0f; iz[k] = (int)z0f;
        inb &= ((unsigned)ix[k] < (unsigned)(VD-1)) &
               ((unsigned)iy[k] < (unsigned)(VD-1)) &
               ((unsigned)iz[k] < (unsigned)(VD-1));
    }

    if (__all(inb)) {
        // ---- interior fast path: ALL 16 loads issued before consumption ----
        float2 p00[ODQ], p01[ODQ], p10[ODQ], p11[ODQ];
        #pragma unroll
        for (int k = 0; k < ODQ; ++k) {
            const int b00 = (iz[k]*VD + iy[k])*VD + ix[k];
            __builtin_memcpy(&p00[k], v + b00,            sizeof(float2));
            __builtin_memcpy(&p01[k], v + b00 + VD,       sizeof(float2));
            __builtin_memcpy(&p10[k], v + b00 + VD*VD,    sizeof(float2));
            __builtin_memcpy(&p11[k], v + b00 + VD*VD+VD, sizeof(float2));
        }
        #pragma unroll
        for (int k = 0; k < ODQ; ++k) {
            const float r00 = fmaf(fx[k], p00[k].y - p00[k].x, p00[k].x);
            const float r01 = fmaf(fx[k], p01[k].y - p01[k].x, p01[k].x);
            const float r10 = fmaf(fx[k], p10[k].y - p10[k].x, p10[k].x);
            const float r11 = fmaf(fx[k], p11[k].y - p11[k].x, p11[k].x);
            const float r0 = fmaf(fy[k], r01 - r00, r00);
            const float r1 = fmaf(fy[k], r11 - r10, r10);
            const float r  = fmaf(fz[k], r1 - r0, r0);
            __builtin_nontemporal_store(r, op + (size_t)k*OD*OD);
        }
    } else {
        // ---- border path: full predicated weights + clamps (rare) ----
        #pragma unroll
        for (int k = 0; k < ODQ; ++k) {
            const int ix1 = ix[k] + 1, iy1 = iy[k] + 1, iz1 = iz[k] + 1;

            const float WX0 = ((unsigned)ix[k] < (unsigned)VD) ? (1.0f - fx[k]) : 0.0f;
            const float WX1 = ((unsigned)ix1   < (unsigned)VD) ? fx[k]          : 0.0f;
            const float WY0 = ((unsigned)iy[k] < (unsigned)VD) ? (1.0f - fy[k]) : 0.0f;
            const float WY1 = ((unsigned)iy1   < (unsigned)VD) ? fy[k]          : 0.0f;
            const float WZ0 = ((unsigned)iz[k] < (unsigned)VD) ? (1.0f - fz[k]) : 0.0f;
            const float WZ1 = ((unsigned)iz1   < (unsigned)VD) ? fz[k]          : 0.0f;

            const int xc0 = min(max(ix[k], 0), VD-1), xc1 = min(max(ix1, 0), VD-1);
            const int yc0 = min(max(iy[k], 0), VD-1), yc1 = min(max(iy1, 0), VD-1);
            const int zc0 = min(max(iz[k], 0), VD-1), zc1 = min(max(iz1, 0), VD-1);

            // one dwordx2 covers both x-taps; fold x-selection into wA/wB
            const int base = min(xc0, VD-2);
            const bool hi0 = (xc0 != base);
            const bool hi1 = (xc1 != base);
            const float wA = (hi0 ? 0.0f : WX0) + (hi1 ? 0.0f : WX1);
            const float wB = (hi0 ? WX0 : 0.0f) + (hi1 ? WX1 : 0.0f);

            const int sA = zc0*(VD*VD), sB = zc1*(VD*VD);
            const int tA = yc0*VD + base, tB = yc1*VD + base;

            float2 p00, p01, p10, p11;
            __builtin_memcpy(&p00, v + sA + tA, sizeof(float2));
            __builtin_memcpy(&p01, v + sA + tB, sizeof(float2));
            __builtin_memcpy(&p10, v + sB + tA, sizeof(float2));
            __builtin_memcpy(&p11, v + sB + tB, sizeof(float2));

            const float r00 = p00.x*wA + p00.y*wB;
            const float r01 = p01.x*wA + p01.y*wB;
            const float r10 = p10.x*wA + p10.y*wB;
            const float r11 = p11.x*wA + p11.y*wB;
            const float r = (r00*WY0 + r01*WY1)*WZ0 + (r10*WY0 + r11*WY1)*WZ1;

            __builtin_nontemporal_store(r, op + (size_t)k*OD*OD);
        }
    }
}

// ---------------------------------------------------------------------------
extern "C" void kernel_launch(void* const* d_in, const int* in_sizes, int n_in,
                              void* d_out, int out_size, void* d_ws, size_t ws_size,
                              hipStream_t stream) {
    const float* vol   = (const float*)d_in[0];
    const float* rot   = (const float*)d_in[1];
    const float* scale = (const float*)d_in[2];
    const float* shift = (const float*)d_in[3];
    const float* dz    = (const float*)d_in[4];
    const float* dy    = (const float*)d_in[5];
    const float* dx    = (const float*)d_in[6];
    float* out = (float*)d_out;

    float* ws     = (float*)d_ws;
    float* theta  = ws;         // 4*12 = 48 floats
    float* fields = ws + 48;    // 3*1331 floats

    prep_kernel<<<4, 1024, 0, stream>>>(rot, scale, shift, dz, dy, dx,
                                        theta, fields);
    dim3 grid(OD/32, OD/8, (OD/8)*NBATCH);
    sample_kernel<<<grid, 512, 0, stream>>>(vol, theta, fields, out);
}